// Round 2
// baseline (269.192 us; speedup 1.0000x reference)
//
#include <hip/hip_runtime.h>
#include <math.h>

#define DIM 4096
#define CAP 8192
#define EPS 1e-8f
#define MAXK 16

// ---------------------------------------------------------------------------
// Kernel A: wave-per-row cosine score. 2048 blocks x 256 threads = 8192 waves,
// one wave per memory row. No barriers, no LDS — pure shuffle reduction.
// Each lane: 16 coalesced float4 loads of the row (+16 L1-hit query loads).
// ---------------------------------------------------------------------------
__global__ __launch_bounds__(256) void score_kernel(
    const float* __restrict__ q,
    const float* __restrict__ mb,
    const float* __restrict__ imp,
    const float* __restrict__ age,
    float* __restrict__ weighted)
{
    const int lane = threadIdx.x & 63;
    const int row  = (blockIdx.x << 2) + (threadIdx.x >> 6);

    const float4* __restrict__ mrow = (const float4*)(mb + (size_t)row * DIM);
    const float4* __restrict__ q4   = (const float4*)q;

    float dot = 0.f, msq = 0.f, qsq = 0.f;
    #pragma unroll
    for (int it = 0; it < 16; ++it) {
        const int i = lane + (it << 6);          // stride-64 float4: coalesced 1 KiB/inst
        float4 m  = mrow[i];
        float4 qq = q4[i];
        dot = fmaf(m.x, qq.x, fmaf(m.y, qq.y, fmaf(m.z, qq.z, fmaf(m.w, qq.w, dot))));
        msq = fmaf(m.x, m.x,  fmaf(m.y, m.y,  fmaf(m.z, m.z,  fmaf(m.w, m.w,  msq))));
        qsq = fmaf(qq.x, qq.x, fmaf(qq.y, qq.y, fmaf(qq.z, qq.z, fmaf(qq.w, qq.w, qsq))));
    }

    #pragma unroll
    for (int off = 32; off > 0; off >>= 1) {
        dot += __shfl_down(dot, off, 64);
        msq += __shfl_down(msq, off, 64);
        qsq += __shfl_down(qsq, off, 64);
    }

    if (lane == 0) {
        float denom = fmaxf(sqrtf(qsq) * sqrtf(msq), EPS);
        weighted[row] = (dot / denom) * imp[row] * expf(-0.001f * age[row]);
    }
}

// ---------------------------------------------------------------------------
// Kernel B: top-k by wave 0 only (barrier-free repeated argmax over LDS with
// float4 scans, lowest-index tie-break = jax.lax.top_k semantics), then
// gather-mean with all 256 threads.
// ---------------------------------------------------------------------------
__global__ __launch_bounds__(256) void topk_gather_kernel(
    const float* __restrict__ weighted,
    const float* __restrict__ mb,
    const int* __restrict__ topk_ptr,
    float* __restrict__ retrieved)
{
    __shared__ float wv[CAP];                    // 32 KiB
    __shared__ int   sidx[MAXK];

    const int tid = threadIdx.x;
    int k = *topk_ptr;
    k = (k < 1) ? 1 : (k > MAXK ? MAXK : k);

    // stage scores into LDS with all 256 threads
    const float4* __restrict__ w4 = (const float4*)weighted;
    float4* wv4 = (float4*)wv;
    for (int i = tid; i < CAP / 4; i += 256) wv4[i] = w4[i];
    __syncthreads();

    if (tid < 64) {                              // wave 0 only: no barriers inside
        for (int it = 0; it < k; ++it) {
            float bv = -INFINITY;
            int   bi = 0x7fffffff;
            for (int i = tid; i < CAP / 4; i += 64) {
                float4 v = wv4[i];
                const int base = i << 2;
                // ascending index + strict > keeps the lowest index per lane
                if (v.x > bv) { bv = v.x; bi = base; }
                if (v.y > bv) { bv = v.y; bi = base + 1; }
                if (v.z > bv) { bv = v.z; bi = base + 2; }
                if (v.w > bv) { bv = v.w; bi = base + 3; }
            }
            #pragma unroll
            for (int off = 32; off > 0; off >>= 1) {
                float ov = __shfl_down(bv, off, 64);
                int   oi = __shfl_down(bi, off, 64);
                if (ov > bv || (ov == bv && oi < bi)) { bv = ov; bi = oi; }
            }
            const int best = __shfl(bi, 0, 64);  // broadcast winner to all lanes
            if (tid == 0) sidx[it] = best;
            wv[best] = -INFINITY;                // all lanes, same addr/value: safe,
                                                 // guarantees per-lane write->read order
        }
    }
    __syncthreads();

    // gather-mean of the k selected rows, all 256 threads
    const float inv_k = 1.0f / (float)k;
    for (int i = tid; i < DIM / 4; i += 256) {
        float ax = 0.f, ay = 0.f, az = 0.f, aw = 0.f;
        for (int r = 0; r < k; ++r) {
            const float4 v = ((const float4*)(mb + (size_t)sidx[r] * DIM))[i];
            ax += v.x; ay += v.y; az += v.z; aw += v.w;
        }
        ((float4*)retrieved)[i] = make_float4(ax * inv_k, ay * inv_k, az * inv_k, aw * inv_k);
    }
}

// ---------------------------------------------------------------------------
// Kernel C: wave-per-output-row decode. 1024 blocks x 256 threads = 4096 waves.
// out[j] = dot(W_dec[j,:], retrieved) + b_dec[j]. No barriers, no LDS.
// ---------------------------------------------------------------------------
__global__ __launch_bounds__(256) void decode_kernel(
    const float* __restrict__ W,
    const float* __restrict__ b,
    const float* __restrict__ r,
    float* __restrict__ out)
{
    const int lane = threadIdx.x & 63;
    const int j    = (blockIdx.x << 2) + (threadIdx.x >> 6);

    const float4* __restrict__ wrow = (const float4*)(W + (size_t)j * DIM);
    const float4* __restrict__ r4   = (const float4*)r;

    float acc = 0.f;
    #pragma unroll
    for (int it = 0; it < 16; ++it) {
        const int i = lane + (it << 6);
        float4 w = wrow[i];
        float4 v = r4[i];
        acc = fmaf(w.x, v.x, fmaf(w.y, v.y, fmaf(w.z, v.z, fmaf(w.w, v.w, acc))));
    }

    #pragma unroll
    for (int off = 32; off > 0; off >>= 1) acc += __shfl_down(acc, off, 64);

    if (lane == 0) out[j] = acc + b[j];
}

extern "C" void kernel_launch(void* const* d_in, const int* in_sizes, int n_in,
                              void* d_out, int out_size, void* d_ws, size_t ws_size,
                              hipStream_t stream) {
    const float* query      = (const float*)d_in[0];
    const float* memory     = (const float*)d_in[1];
    const float* importance = (const float*)d_in[2];
    const float* age        = (const float*)d_in[3];
    const float* W_dec      = (const float*)d_in[4];
    const float* b_dec      = (const float*)d_in[5];
    const int*   top_k      = (const int*)d_in[6];

    float* weighted  = (float*)d_ws;             // CAP floats
    float* retrieved = (float*)d_ws + CAP;       // DIM floats
    float* out       = (float*)d_out;

    score_kernel<<<CAP / 4, 256, 0, stream>>>(query, memory, importance, age, weighted);
    topk_gather_kernel<<<1, 256, 0, stream>>>(weighted, memory, top_k, retrieved);
    decode_kernel<<<DIM / 4, 256, 0, stream>>>(W_dec, b_dec, retrieved, out);
}